// Round 23
// baseline (103.832 us; speedup 1.0000x reference)
//
#include <hip/hip_runtime.h>
#include <math.h>

#define NHEADS 16
#define HD 64

typedef __attribute__((ext_vector_type(8))) _Float16 half8;
typedef __attribute__((ext_vector_type(4))) _Float16 half4;
typedef __attribute__((ext_vector_type(4))) float f32x4;
typedef __attribute__((ext_vector_type(16))) float f32x16;
typedef __attribute__((ext_vector_type(4))) unsigned int u32x4;

__device__ inline void load_lds16(const void* g, void* l) {
    __builtin_amdgcn_global_load_lds(
        (const __attribute__((address_space(1))) unsigned int*)g,
        (__attribute__((address_space(3))) unsigned int*)l, 16, 0, 0);
}
__device__ inline void pl32swap(unsigned int& x, unsigned int& y) {
    asm volatile("v_permlane32_swap_b32 %0, %1" : "+v"(x), "+v"(y));
}

// fp32 -> fp16 for x, w_qkv, w_o in ONE launch. Segment by flat index.
#define NX  4194304   // 4096*1024
#define NWQ 3145728   // 3072*1024
#define NWO 1048576   // 1024*1024
__global__ void cvt_all(const float* __restrict__ x, const float* __restrict__ wq,
                        const float* __restrict__ wo, _Float16* __restrict__ xf,
                        _Float16* __restrict__ wqf, _Float16* __restrict__ wof) {
    int i = (blockIdx.x * blockDim.x + threadIdx.x) * 8;
    const float* src; _Float16* dst; int off;
    if (i < NX)            { src = x;  dst = xf;  off = i; }
    else if (i < NX + NWQ) { src = wq; dst = wqf; off = i - NX; }
    else                   { src = wo; dst = wof; off = i - (NX + NWQ); }
    float4 a = *(const float4*)(src + off);
    float4 b = *(const float4*)(src + off + 4);
    half8 h;
    h[0] = (_Float16)a.x; h[1] = (_Float16)a.y; h[2] = (_Float16)a.z; h[3] = (_Float16)a.w;
    h[4] = (_Float16)b.x; h[5] = (_Float16)b.y; h[6] = (_Float16)b.z; h[7] = (_Float16)b.w;
    *(half8*)(dst + off) = h;
}

// ============ gemm_qkv: 256x192 tile, BK=64, 8-phase (race-free), grid 256 ====
#define QSCALE 0.18033688f
__global__ __launch_bounds__(512, 2) void gemm_qkv(
    const _Float16* __restrict__ A, const _Float16* __restrict__ B,
    const float* __restrict__ bias,
    _Float16* __restrict__ Qf, _Float16* __restrict__ Kf,
    _Float16* __restrict__ VfT) {
    __shared__ __align__(1024) unsigned char smem[114688];
    const int tid = threadIdx.x;
    const int l = tid & 63, w = tid >> 6;          // 8 waves
    const int wr = w >> 2, wc = w & 3;             // 2 x 4
    const int col16 = l & 15, kc = l >> 4;
    const int bid = blockIdx.y * gridDim.x + blockIdx.x;   // grid 16 x 16 = 256
    const int swz = (bid & 7) * 32 + (bid >> 3);           // XCD swizzle (256%8==0)
    const int m0 = (swz >> 4) * 256, n0 = (swz & 15) * 192;

    const int srcRow = w * 8 + (l >> 3);
    const int srcChunk = ((l & 7) ^ (l >> 3)) * 8;
    size_t aSrc[4], bSrc[3];
    #pragma unroll
    for (int q = 0; q < 4; ++q)
        aSrc[q] = (size_t)(m0 + q * 64 + srcRow) * 1024 + srcChunk;
    #pragma unroll
    for (int q = 0; q < 3; ++q)
        bSrc[q] = (size_t)(n0 + q * 64 + srcRow) * 1024 + srcChunk;
    const int ldsLane = w * 1024;

    const int swzl = col16 & 7;
    const int chOff0 = ((kc) ^ swzl) << 4;
    const int chOff1 = ((4 + kc) ^ swzl) << 4;
    int rowA[8], rowB[3];
    #pragma unroll
    for (int f = 0; f < 8; ++f) rowA[f] = (wr * 128 + f * 16 + col16) * 128;
    #pragma unroll
    for (int g = 0; g < 3; ++g) rowB[g] = (wc * 48 + g * 16 + col16) * 128;

    f32x4 acc[8][3] = {};

#define SU_A(q_, tt_) load_lds16(A + aSrc[q_] + (tt_) * 64, \
        smem + ((tt_) & 1) * 32768 + (q_) * 8192 + ldsLane);
#define SU_B(q_, tt_) load_lds16(B + bSrc[q_] + (tt_) * 64, \
        smem + 65536 + ((tt_) & 1) * 24576 + (q_) * 8192 + ldsLane);

#define VMW2 asm volatile("s_waitcnt vmcnt(2)" ::: "memory");
#define VMW3 asm volatile("s_waitcnt vmcnt(3)" ::: "memory");
#define VMW0 asm volatile("s_waitcnt vmcnt(0)" ::: "memory");

#define PH(mh_, g0_, gn_, bufA_, bufB_, VMWSTMT, STAGES) { \
    VMWSTMT \
    __builtin_amdgcn_sched_barrier(0); \
    __builtin_amdgcn_s_barrier(); \
    __builtin_amdgcn_sched_barrier(0); \
    half8 af[4][2], bf[gn_][2]; \
    _Pragma("unroll") \
    for (int f = 0; f < 4; ++f) { \
        const unsigned char* ap = smem + (bufA_) + rowA[(mh_) * 4 + f]; \
        af[f][0] = *(const half8*)(ap + chOff0); \
        af[f][1] = *(const half8*)(ap + chOff1); \
    } \
    _Pragma("unroll") \
    for (int g = 0; g < (gn_); ++g) { \
        const unsigned char* bp = smem + (bufB_) + rowB[(g0_) + g]; \
        bf[g][0] = *(const half8*)(bp + chOff0); \
        bf[g][1] = *(const half8*)(bp + chOff1); \
    } \
    STAGES \
    asm volatile("s_waitcnt lgkmcnt(0)" ::: "memory"); \
    __builtin_amdgcn_sched_barrier(0); \
    __builtin_amdgcn_s_setprio(1); \
    _Pragma("unroll") \
    for (int f = 0; f < 4; ++f) \
        _Pragma("unroll") \
        for (int g = 0; g < (gn_); ++g) { \
            acc[(mh_) * 4 + f][(g0_) + g] = __builtin_amdgcn_mfma_f32_16x16x32_f16( \
                af[f][0], bf[g][0], acc[(mh_) * 4 + f][(g0_) + g], 0, 0, 0); \
            acc[(mh_) * 4 + f][(g0_) + g] = __builtin_amdgcn_mfma_f32_16x16x32_f16( \
                af[f][1], bf[g][1], acc[(mh_) * 4 + f][(g0_) + g], 0, 0, 0); \
        } \
    __builtin_amdgcn_s_setprio(0); }

    SU_B(0, 0) SU_B(1, 0) SU_B(2, 0)
    SU_A(0, 0) SU_A(2, 0) SU_A(1, 0) SU_A(3, 0)

    for (int t = 0; t < 15; ++t) {
        const int bufA = (t & 1) * 32768;
        const int bufB = 65536 + (t & 1) * 24576;
        PH(0, 0, 2, bufA, bufB, VMW2, { SU_B(0, t + 1) SU_B(1, t + 1) })
        PH(0, 2, 1, bufA, bufB, ,     { SU_B(2, t + 1) })
        PH(1, 0, 2, bufA, bufB, VMW3, { SU_A(0, t + 1) SU_A(2, t + 1) })
        PH(1, 2, 1, bufA, bufB, ,     { SU_A(1, t + 1) SU_A(3, t + 1) })
    }
    PH(0, 0, 2, 32768, 65536 + 24576, VMW2, {})
    PH(0, 2, 1, 32768, 65536 + 24576, ,     {})
    PH(1, 0, 2, 32768, 65536 + 24576, VMW0, {})
    PH(1, 2, 1, 32768, 65536 + 24576, ,     {})

#undef SU_A
#undef SU_B
#undef VMW2
#undef VMW3
#undef VMW0
#undef PH

    const int rowb = m0 + wr * 128 + (l >> 4) * 4;
    const int colb = n0 + wc * 48 + col16;
    #pragma unroll
    for (int n = 0; n < 3; ++n) {
        int col = colb + n * 16;
        int h = col / 192;
        int rem = col - h * 192;
        int part = rem >> 6, d = rem & 63;
        float bv = bias[col];
        #pragma unroll
        for (int m = 0; m < 8; ++m) {
            int r0 = rowb + m * 16;
            int b = r0 >> 11, s0r = r0 & 2047;
            int bh = b * 16 + h;
            if (part == 0) {
                #pragma unroll
                for (int j = 0; j < 4; ++j)
                    Qf[((size_t)bh * 2048 + s0r + j) * 64 + d] =
                        (_Float16)((acc[m][n][j] + bv) * QSCALE);
            } else if (part == 1) {
                #pragma unroll
                for (int j = 0; j < 4; ++j)
                    Kf[((size_t)bh * 2048 + s0r + j) * 64 + d] = (_Float16)(acc[m][n][j] + bv);
            } else {
                half4 pk;
                pk[0] = (_Float16)(acc[m][n][0] + bv);
                pk[1] = (_Float16)(acc[m][n][1] + bv);
                pk[2] = (_Float16)(acc[m][n][2] + bv);
                pk[3] = (_Float16)(acc[m][n][3] + bv);
                *(half4*)&VfT[((size_t)bh * 64 + d) * 2048 + s0r] = pk;
            }
        }
    }
}

// out[M,N] = A[M,K] @ B[N,K]^T + bias, f32 out. 128x64 tile, 3-buffer pipeline.
__global__ __launch_bounds__(256, 2) void gemm_o(
    const _Float16* __restrict__ A, const _Float16* __restrict__ B,
    const float* __restrict__ bias, float* __restrict__ C,
    int M, int N, int K) {
    __shared__ __align__(1024) unsigned char smem[36864];
    const int tid = threadIdx.x;
    const int l = tid & 63, w = tid >> 6;
    const int wr = w >> 1, wc = w & 1;
    const int nwg = gridDim.x * gridDim.y;
    const int bid = blockIdx.y * gridDim.x + blockIdx.x;
    const int swz = (bid & 7) * (nwg >> 3) + (bid >> 3);
    const int m0 = (swz / gridDim.x) * 128, n0 = (swz % gridDim.x) * 64;
    const int srow = tid >> 2;
    const int schunk = (tid & 3) ^ ((srow >> 1) & 3);
    const size_t gA0 = (size_t)(m0 + srow) * K + schunk * 8;
    const size_t gA1 = gA0 + (size_t)64 * K;
    const size_t gB0 = (size_t)(n0 + srow) * K + schunk * 8;
    unsigned char* ldsW = smem + w * 1024;
    const int col16 = l & 15, kc = l >> 4;
    const int ra0 = wr * 64 + col16;
    const int offA = ra0 * 64 + ((kc ^ ((ra0 >> 1) & 3)) * 16);
    const int rb0 = wc * 32 + col16;
    const int offB = rb0 * 64 + ((kc ^ ((rb0 >> 1) & 3)) * 16);
    f32x4 acc[4][2] = {};

#define OSTAGE(k0_, buf_)                                                              \
    load_lds16(A + gA0 + (k0_), ldsW + (buf_) * 12288 + 0);                            \
    load_lds16(A + gA1 + (k0_), ldsW + (buf_) * 12288 + 4096);                         \
    load_lds16(B + gB0 + (k0_), ldsW + (buf_) * 12288 + 8192);
#define OSTEP(s_, buf_, VM, dostage)                                                   \
    asm volatile("s_waitcnt " VM ::: "memory");                                        \
    __builtin_amdgcn_sched_barrier(0);                                                 \
    __builtin_amdgcn_s_barrier();                                                      \
    if (dostage) { OSTAGE(((s_) + 2) * 32, ((buf_) + 2) % 3) }                         \
    {                                                                                  \
        const unsigned char* bs = smem + (buf_) * 12288;                               \
        half8 af[4], bf[2];                                                            \
        _Pragma("unroll")                                                              \
        for (int m = 0; m < 4; ++m) af[m] = *(const half8*)(bs + offA + m * 1024);     \
        _Pragma("unroll")                                                              \
        for (int n = 0; n < 2; ++n) bf[n] = *(const half8*)(bs + 8192 + offB + n * 1024); \
        _Pragma("unroll")                                                              \
        for (int m = 0; m < 4; ++m)                                                    \
            _Pragma("unroll")                                                          \
            for (int n = 0; n < 2; ++n)                                                \
                acc[m][n] = __builtin_amdgcn_mfma_f32_16x16x32_f16(af[m], bf[n], acc[m][n], 0, 0, 0); \
    }

    OSTAGE(0, 0)
    OSTAGE(32, 1)
    for (int t = 0; t < 30; t += 3) {
        OSTEP(t, 0, "vmcnt(3)", 1)
        OSTEP(t + 1, 1, "vmcnt(3)", 1)
        OSTEP(t + 2, 2, "vmcnt(3)", 1)
    }
    OSTEP(30, 0, "vmcnt(3)", 0)
    OSTEP(31, 1, "vmcnt(0)", 0)
#undef OSTAGE
#undef OSTEP

    const int rowb = m0 + wr * 64 + (l >> 4) * 4;
    const int colb = n0 + wc * 32 + col16;
    float bv[2];
    #pragma unroll
    for (int n = 0; n < 2; ++n) bv[n] = bias[colb + n * 16];
    #pragma unroll
    for (int m = 0; m < 4; ++m)
        #pragma unroll
        for (int j = 0; j < 4; ++j) {
            float* crow = C + (size_t)(rowb + m * 16 + j) * N + colb;
            #pragma unroll
            for (int n = 0; n < 2; ++n) crow[n * 16] = acc[m][n][j] + bv[n];
        }
}

// MFMA flash attention: 64-q WAVES x 2 BLOCKS/CU.
// 4 waves of 256-thread block; wave w owns q [w*64, w*64+64) as two 32-q groups
// (A/B) sharing every K/V fragment read (each read feeds 4 MFMAs). q-tile 256,
// grid 256 -> 2 co-resident blocks/CU (indep barriers) = 4 waves/SIMD.
// 3-slot K/V LDS (48KB), counted vmcnt, absolute-score softmax, in-register P.
__global__ __launch_bounds__(256, 2) void mfma_attn(
    const _Float16* __restrict__ Qf, const _Float16* __restrict__ Kf,
    const _Float16* __restrict__ VfT, _Float16* __restrict__ vals) {
    __shared__ __align__(1024) unsigned char smem[49152];  // slot i: K @ i*16K, V @ i*16K+8K
    const int tid = threadIdx.x;
    const int l = tid & 63, w = tid >> 6;          // 4 waves
    const int l31 = l & 31, hl = l >> 5;
    const int hwbid = blockIdx.y * gridDim.x + blockIdx.x;
    const int q_t = (hwbid >> 3) & 7;
    const int bh = (hwbid & 7) + ((hwbid >> 6) << 3);
    const int q0 = q_t * 256;
    const int h = bh & 15, b = bh >> 4;

    half8 qfA[4], qfB[4];
    {
        const _Float16* qp = Qf + ((size_t)bh * 2048 + q0 + w * 64 + l31) * 64 + hl * 8;
        #pragma unroll
        for (int c = 0; c < 4; ++c) qfA[c] = *(const half8*)(qp + c * 16);
        qp += (size_t)32 * 64;
        #pragma unroll
        for (int c = 0; c < 4; ++c) qfB[c] = *(const half8*)(qp + c * 16);
    }
    f32x16 zvec = {};
    f32x16 oA0 = {}, oA1 = {}, oB0 = {}, oB1 = {};
    float msA = 0.f, msB = 0.f, lsA = 0.f, lsB = 0.f;

    const _Float16* Kg = Kf + (size_t)bh * 2048 * 64;
    const _Float16* Vg = VfT + (size_t)bh * 64 * 2048;

    // staging: 4 waves cover 32 row-pairs x 16 slots; 2 K + 2 V loads each
    int offK[2], offV[2];
    #pragma unroll
    for (int i = 0; i < 2; ++i) {
        int row2 = w * 8 + i * 4 + (l >> 4);
        int slot = (l & 15) ^ (row2 & 15);
        int row = row2 * 2 + (slot >> 3);
        int chunk = slot & 7;
        offK[i] = row * 64 + chunk * 8;
        offV[i] = row * 2048 + chunk * 8;
    }
    const int sbase = (l31 & 1) * 8;
    const int xr = (l31 >> 1) & 15;
    const int rb0 = (l31 >> 1) * 256;

    #define STAGE(kt0, buf)                                                            \
        {                                                                              \
            unsigned char* bK = smem + (buf) * 16384 + w * 2048;                       \
            unsigned char* bV = bK + 8192;                                             \
            load_lds16(Kg + (size_t)(kt0) * 64 + offK[0], bK);                         \
            load_lds16(Kg + (size_t)(kt0) * 64 + offK[1], bK + 1024);                  \
            load_lds16(Vg + (kt0) + offV[0], bV);                                      \
            load_lds16(Vg + (kt0) + offV[1], bV + 1024);                               \
        }

    // QK for both q-groups off the same K reads
    #define QK2(slot_)                                                                 \
        {                                                                              \
            const unsigned char* Ksb_ = smem + (slot_) * 16384;                        \
            {                                                                          \
                int chOff = ((sbase + hl) ^ xr) << 4;                                  \
                half8 k0_ = *(const half8*)(Ksb_ + rb0 + chOff);                       \
                half8 k1_ = *(const half8*)(Ksb_ + rb0 + 4096 + chOff);                \
                sA0 = __builtin_amdgcn_mfma_f32_32x32x16_f16(k0_, qfA[0], zvec, 0, 0, 0); \
                sA1 = __builtin_amdgcn_mfma_f32_32x32x16_f16(k1_, qfA[0], zvec, 0, 0, 0); \
                sB0 = __builtin_amdgcn_mfma_f32_32x32x16_f16(k0_, qfB[0], zvec, 0, 0, 0); \
                sB1 = __builtin_amdgcn_mfma_f32_32x32x16_f16(k1_, qfB[0], zvec, 0, 0, 0); \
            }                                                                          \
            _Pragma("unroll")                                                          \
            for (int kc = 1; kc < 4; ++kc) {                                           \
                int chOff = ((sbase + kc * 2 + hl) ^ xr) << 4;                         \
                half8 k0_ = *(const half8*)(Ksb_ + rb0 + chOff);                       \
                half8 k1_ = *(const half8*)(Ksb_ + rb0 + 4096 + chOff);                \
                sA0 = __builtin_amdgcn_mfma_f32_32x32x16_f16(k0_, qfA[kc], sA0, 0, 0, 0); \
                sA1 = __builtin_amdgcn_mfma_f32_32x32x16_f16(k1_, qfA[kc], sA1, 0, 0, 0); \
                sB0 = __builtin_amdgcn_mfma_f32_32x32x16_f16(k0_, qfB[kc], sB0, 0, 0, 0); \
                sB1 = __builtin_amdgcn_mfma_f32_32x32x16_f16(k1_, qfB[kc], sB1, 0, 0, 0); \
            }                                                                          \
        }

    // softmax for one group (updates O/ls/ms, emits packed P into AA)
    #define SM_G(S0, S1, O0, O1, AA, ls_, ms_)                                         \
        {                                                                              \
            if (__any(ms_ != 0.f)) {                                                   \
                _Pragma("unroll")                                                      \
                for (int r = 0; r < 16; ++r) { S0[r] -= ms_; S1[r] -= ms_; }           \
            }                                                                          \
            float r0 = 0.f, r1 = 0.f, r2 = 0.f, r3 = 0.f;                              \
            _Pragma("unroll")                                                          \
            for (int j = 0; j < 8; ++j) {                                              \
                float p0 = __builtin_amdgcn_exp2f(S0[2 * j]);                          \
                float p1 = __builtin_amdgcn_exp2f(S0[2 * j + 1]);                      \
                float q0_ = __builtin_amdgcn_exp2f(S1[2 * j]);                         \
                float q1_ = __builtin_amdgcn_exp2f(S1[2 * j + 1]);                     \
                r0 += p0; r1 += p1; r2 += q0_; r3 += q1_;                              \
                AA[0][j] = __builtin_bit_cast(unsigned int, __builtin_amdgcn_cvt_pkrtz(p0, p1));   \
                AA[1][j] = __builtin_bit_cast(unsigned int, __builtin_amdgcn_cvt_pkrtz(q0_, q1_)); \
            }                                                                          \
            float rsum = (r0 + r1) + (r2 + r3);                                        \
            if (__any(rsum > 32768.f)) {                                               \
                float pmax = S0[0];                                                    \
                _Pragma("unroll")                                                      \
                for (int r = 1; r < 16; ++r) pmax = fmaxf(pmax, S0[r]);                \
                _Pragma("unroll")                                                      \
                for (int r = 0; r < 16; ++r) pmax = fmaxf(pmax, S1[r]);                \
                pmax = fmaxf(pmax, __shfl_xor(pmax, 32, 64));                          \
                float d_ = fmaxf(pmax, 0.f);                                           \
                float corr = __builtin_amdgcn_exp2f(-d_);                              \
                _Pragma("unroll")                                                      \
                for (int r = 0; r < 16; ++r) { S0[r] -= d_; S1[r] -= d_; }             \
                _Pragma("unroll")                                                      \
                for (int r = 0; r < 16; ++r) { O0[r] *= corr; O1[r] *= corr; }         \
                ls_ *= corr;                                                           \
                ms_ += d_;                                                             \
                r0 = r1 = r2 = r3 = 0.f;                                               \
                _Pragma("unroll")                                                      \
                for (int j = 0; j < 8; ++j) {                                          \
                    float p0 = __builtin_amdgcn_exp2f(S0[2 * j]);                      \
                    float p1 = __builtin_amdgcn_exp2f(S0[2 * j + 1]);                  \
                    float q0_ = __builtin_amdgcn_exp2f(S1[2 * j]);                     \
                    float q1_ = __builtin_amdgcn_exp2f(S1[2 * j + 1]);                 \
                    r0 += p0; r1 += p1; r2 += q0_; r3 += q1_;                          \
                    AA[0][j] = __builtin_bit_cast(unsigned int, __builtin_amdgcn_cvt_pkrtz(p0, p1));   \
                    AA[1][j] = __builtin_bit_cast(unsigned int, __builtin_amdgcn_cvt_pkrtz(q0_, q1_)); \
                }                                                                      \
                rsum = (r0 + r1) + (r2 + r3);                                          \
            }                                                                          \
            ls_ += rsum;                                                               \
            _Pragma("unroll")                                                          \
            for (int c = 0; c < 2; ++c) {                                              \
                pl32swap(AA[c][0], AA[c][2]);                                          \
                pl32swap(AA[c][1], AA[c][3]);                                          \
                pl32swap(AA[c][4], AA[c][6]);                                          \
                pl32swap(AA[c][5], AA[c][7]);                                          \
            }                                                                          \
        }

    // PV for both groups off the same V reads
    #define PV2(slot_)                                                                 \
        {                                                                              \
            const unsigned char* Vsb_ = smem + (slot_) * 16384 + 8192;                 \
            _Pragma("unroll")                                                          \
            for (int kk = 0; kk < 4; ++kk) {                                           \
                u32x4 pwA, pwB;                                                        \
                pwA.x = aA[kk >> 1][(kk & 1) * 4 + 0];                                 \
                pwA.y = aA[kk >> 1][(kk & 1) * 4 + 1];                                 \
                pwA.z = aA[kk >> 1][(kk & 1) * 4 + 2];                                 \
                pwA.w = aA[kk >> 1][(kk & 1) * 4 + 3];                                 \
                pwB.x = aB[kk >> 1][(kk & 1) * 4 + 0];                                 \
                pwB.y = aB[kk >> 1][(kk & 1) * 4 + 1];                                 \
                pwB.z = aB[kk >> 1][(kk & 1) * 4 + 2];                                 \
                pwB.w = aB[kk >> 1][(kk & 1) * 4 + 3];                                 \
                half8 pfA = __builtin_bit_cast(half8, pwA);                            \
                half8 pfB = __builtin_bit_cast(half8, pwB);                            \
                int chOff = ((sbase + kk * 2 + hl) ^ xr) << 4;                         \
                half8 v0 = *(const half8*)(Vsb_ + rb0 + chOff);                        \
                half8 v1 = *(const half8*)(Vsb_ + rb0 + 4096 + chOff);                 \
                oA0 = __builtin_amdgcn_mfma_f32_32x32x16_f16(v0, pfA, oA0, 0, 0, 0);   \
                oA1 = __builtin_amdgcn_mfma_f32_32x32x16_f16(v1, pfA, oA1, 0, 0, 0);   \
                oB0 = __builtin_amdgcn_mfma_f32_32x32x16_f16(v0, pfB, oB0, 0, 0, 0);   \
                oB1 = __builtin_amdgcn_mfma_f32_32x32x16_f16(v1, pfB, oB1, 0, 0, 0);   \
            }                                                                          \
        }

    #define AITER(tt, kb, VM, dostage)                                                 \
        asm volatile("s_waitcnt " VM ::: "memory");                                    \
        __builtin_amdgcn_sched_barrier(0);                                             \
        __builtin_amdgcn_s_barrier();                                                  \
        if (dostage) STAGE(((tt) + 2) * 64, ((kb) + 2) % 3)                            \
        QK2(kb)                                                                        \
        {                                                                              \
            unsigned int aA[2][8], aB[2][8];                                           \
            SM_G(sA0, sA1, oA0, oA1, aA, lsA, msA)                                     \
            SM_G(sB0, sB1, oB0, oB1, aB, lsB, msB)                                     \
            PV2(kb)                                                                    \
        }

    STAGE(0, 0)
    STAGE(64, 1)
    f32x16 sA0, sA1, sB0, sB1;
    for (int t = 0; t < 30; t += 3) {
        AITER(t, 0, "vmcnt(4)", 1)
        AITER(t + 1, 1, "vmcnt(4)", 1)
        AITER(t + 2, 2, "vmcnt(4)", 1)
    }
    AITER(30, 0, "vmcnt(4)", 0)
    AITER(31, 1, "vmcnt(0)", 0)

    // ---- epilogue ----
    lsA += __shfl_xor(lsA, 32, 64);
    lsB += __shfl_xor(lsB, 32, 64);
    float invA = 1.f / lsA, invB = 1.f / lsB;
    size_t orowA = ((size_t)(b * 2048 + q0 + w * 64 + l31)) * 1024 + h * 64;
    size_t orowB = orowA + (size_t)32 * 1024;
    #pragma unroll
    for (int dc = 0; dc < 2; ++dc) {
        const f32x16* opA = dc ? &oA1 : &oA0;
        const f32x16* opB = dc ? &oB1 : &oB0;
        #pragma unroll
        for (int rq = 0; rq < 4; ++rq) {
            int d0 = dc * 32 + rq * 8 + hl * 4;
            half4 hvA, hvB;
            #pragma unroll
            for (int j = 0; j < 4; ++j) {
                hvA[j] = (_Float16)((*opA)[rq * 4 + j] * invA);
                hvB[j] = (_Float16)((*opB)[rq * 4 + j] * invB);
            }
            *(half4*)(vals + orowA + d0) = hvA;
            *(half4*)(vals + orowB + d0) = hvB;
        }
    }
}

extern "C" void kernel_launch(void* const* d_in, const int* in_sizes, int n_in,
                              void* d_out, int out_size, void* d_ws, size_t ws_size,
                              hipStream_t stream) {
    const float* x     = (const float*)d_in[0];
    const float* w_qkv = (const float*)d_in[1];
    const float* b_qkv = (const float*)d_in[2];
    const float* w_o   = (const float*)d_in[3];
    const float* b_o   = (const float*)d_in[4];
    float* out = (float*)d_out;

    const int B = 2, S = 2048, D = 1024;
    const int M = B * S;          // 4096
    const int N1 = 3 * D;         // 3072
    const int BH = B * NHEADS;    // 32

    _Float16* xf  = (_Float16*)d_ws;                  // [4096,1024]
    _Float16* wqf = xf  + (size_t)M * D;              // [3072,1024]
    _Float16* wof = wqf + (size_t)N1 * D;             // [1024,1024]
    _Float16* Qf  = wof + (size_t)D * D;              // [32,2048,64]
    _Float16* Kf  = Qf  + (size_t)BH * S * HD;
    _Float16* VfT = Kf  + (size_t)BH * S * HD;        // [32,64,2048]
    _Float16* vals = xf;   // reuse x-f16 space after gemm_qkv

    // 0) all f32->f16 conversions in one launch
    cvt_all<<<(NX + NWQ + NWO) / 2048, 256, 0, stream>>>(x, w_qkv, w_o, xf, wqf, wof);

    // 1) fused QKV projection, 256x192 8-phase, grid 256 (full CU fill)
    gemm_qkv<<<dim3(16, 16), 512, 0, stream>>>(xf, wqf, b_qkv, Qf, Kf, VfT);

    // 2) MFMA flash attention (64-q waves, 2 blocks/CU, counted-vmcnt)
    mfma_attn<<<dim3(S / 256, BH), 256, 0, stream>>>(Qf, Kf, VfT, vals);

    // 3) out = vals @ w_o^T + b_o  (128x64 tile, counted-vmcnt pipeline)
    gemm_o<<<dim3(D / 64, M / 128), 256, 0, stream>>>(vals, wof, b_o, out, M, D, D);
}

// Round 24
// 101.920 us; speedup vs baseline: 1.0188x; 1.0188x over previous
//
#include <hip/hip_runtime.h>
#include <math.h>

#define NHEADS 16
#define HD 64

typedef __attribute__((ext_vector_type(8))) _Float16 half8;
typedef __attribute__((ext_vector_type(4))) _Float16 half4;
typedef __attribute__((ext_vector_type(4))) float f32x4;
typedef __attribute__((ext_vector_type(16))) float f32x16;
typedef __attribute__((ext_vector_type(4))) unsigned int u32x4;

__device__ inline void load_lds16(const void* g, void* l) {
    __builtin_amdgcn_global_load_lds(
        (const __attribute__((address_space(1))) unsigned int*)g,
        (__attribute__((address_space(3))) unsigned int*)l, 16, 0, 0);
}
__device__ inline void pl32swap(unsigned int& x, unsigned int& y) {
    asm volatile("v_permlane32_swap_b32 %0, %1" : "+v"(x), "+v"(y));
}

// fp32 -> fp16 for x, w_qkv, w_o in ONE launch. Segment by flat index.
#define NX  4194304   // 4096*1024
#define NWQ 3145728   // 3072*1024
#define NWO 1048576   // 1024*1024
__global__ void cvt_all(const float* __restrict__ x, const float* __restrict__ wq,
                        const float* __restrict__ wo, _Float16* __restrict__ xf,
                        _Float16* __restrict__ wqf, _Float16* __restrict__ wof) {
    int i = (blockIdx.x * blockDim.x + threadIdx.x) * 8;
    const float* src; _Float16* dst; int off;
    if (i < NX)            { src = x;  dst = xf;  off = i; }
    else if (i < NX + NWQ) { src = wq; dst = wqf; off = i - NX; }
    else                   { src = wo; dst = wof; off = i - (NX + NWQ); }
    float4 a = *(const float4*)(src + off);
    float4 b = *(const float4*)(src + off + 4);
    half8 h;
    h[0] = (_Float16)a.x; h[1] = (_Float16)a.y; h[2] = (_Float16)a.z; h[3] = (_Float16)a.w;
    h[4] = (_Float16)b.x; h[5] = (_Float16)b.y; h[6] = (_Float16)b.z; h[7] = (_Float16)b.w;
    *(half8*)(dst + off) = h;
}

// ============ gemm_qkv: 256x192 tile, BK=64, 8-phase (race-free), grid 256 ====
// 8 waves (2M x 4N), per-wave out 128x48 (8x3 frags). Phase->frags:
// ph(mh,0): A[mh*4..+4] x B[0..1]; ph(mh,1): A[mh*4..+4] x B[2].
// RACE-FREE: per phase, VMW (own loads) -> s_barrier -> ds_reads -> stage
// -> lgkmcnt(0) -> MFMA.  7 loads/tile, strictly distance-1:
//   prologue: B0,B1,B2,A0,A2,A1,A3 (tile 0)
//   ph0 [vmcnt(2)]: stage B0,B1(t+1); ph1: B2(t+1)
//   ph2 [vmcnt(3)]: stage A0,A2(t+1); ph3: A1,A3(t+1)
// LDS 112KB: A buf0 @0, buf1 @32K; B buf0 @64K, buf1 @88K (24KB each).
// Rows 128B, 16B slots XOR-swizzled by (row&7); linear dest + inv-swz source.
#define QSCALE 0.18033688f
__global__ __launch_bounds__(512, 2) void gemm_qkv(
    const _Float16* __restrict__ A, const _Float16* __restrict__ B,
    const float* __restrict__ bias,
    _Float16* __restrict__ Qf, _Float16* __restrict__ Kf,
    _Float16* __restrict__ VfT) {
    __shared__ __align__(1024) unsigned char smem[114688];
    const int tid = threadIdx.x;
    const int l = tid & 63, w = tid >> 6;          // 8 waves
    const int wr = w >> 2, wc = w & 3;             // 2 x 4
    const int col16 = l & 15, kc = l >> 4;
    const int bid = blockIdx.y * gridDim.x + blockIdx.x;   // grid 16 x 16 = 256
    const int swz = (bid & 7) * 32 + (bid >> 3);           // XCD swizzle (256%8==0)
    const int m0 = (swz >> 4) * 256, n0 = (swz & 15) * 192;

    const int srcRow = w * 8 + (l >> 3);                  // row within quarter
    const int srcChunk = ((l & 7) ^ (l >> 3)) * 8;        // elems
    size_t aSrc[4], bSrc[3];
    #pragma unroll
    for (int q = 0; q < 4; ++q)
        aSrc[q] = (size_t)(m0 + q * 64 + srcRow) * 1024 + srcChunk;
    #pragma unroll
    for (int q = 0; q < 3; ++q)
        bSrc[q] = (size_t)(n0 + q * 64 + srcRow) * 1024 + srcChunk;
    const int ldsLane = w * 1024;

    const int swzl = col16 & 7;
    const int chOff0 = ((kc) ^ swzl) << 4;
    const int chOff1 = ((4 + kc) ^ swzl) << 4;
    int rowA[8], rowB[3];
    #pragma unroll
    for (int f = 0; f < 8; ++f) rowA[f] = (wr * 128 + f * 16 + col16) * 128;
    #pragma unroll
    for (int g = 0; g < 3; ++g) rowB[g] = (wc * 48 + g * 16 + col16) * 128;

    f32x4 acc[8][3] = {};

#define SU_A(q_, tt_) load_lds16(A + aSrc[q_] + (tt_) * 64, \
        smem + ((tt_) & 1) * 32768 + (q_) * 8192 + ldsLane);
#define SU_B(q_, tt_) load_lds16(B + bSrc[q_] + (tt_) * 64, \
        smem + 65536 + ((tt_) & 1) * 24576 + (q_) * 8192 + ldsLane);

#define VMW2 asm volatile("s_waitcnt vmcnt(2)" ::: "memory");
#define VMW3 asm volatile("s_waitcnt vmcnt(3)" ::: "memory");
#define VMW0 asm volatile("s_waitcnt vmcnt(0)" ::: "memory");

// Phase: VMW -> barrier -> ds_reads (A frags mh*4.., B frags g0..g0+gn) ->
// stage -> lgkmcnt(0) -> MFMA.
#define PH(mh_, g0_, gn_, bufA_, bufB_, VMWSTMT, STAGES) { \
    VMWSTMT \
    __builtin_amdgcn_sched_barrier(0); \
    __builtin_amdgcn_s_barrier(); \
    __builtin_amdgcn_sched_barrier(0); \
    half8 af[4][2], bf[gn_][2]; \
    _Pragma("unroll") \
    for (int f = 0; f < 4; ++f) { \
        const unsigned char* ap = smem + (bufA_) + rowA[(mh_) * 4 + f]; \
        af[f][0] = *(const half8*)(ap + chOff0); \
        af[f][1] = *(const half8*)(ap + chOff1); \
    } \
    _Pragma("unroll") \
    for (int g = 0; g < (gn_); ++g) { \
        const unsigned char* bp = smem + (bufB_) + rowB[(g0_) + g]; \
        bf[g][0] = *(const half8*)(bp + chOff0); \
        bf[g][1] = *(const half8*)(bp + chOff1); \
    } \
    STAGES \
    asm volatile("s_waitcnt lgkmcnt(0)" ::: "memory"); \
    __builtin_amdgcn_sched_barrier(0); \
    __builtin_amdgcn_s_setprio(1); \
    _Pragma("unroll") \
    for (int f = 0; f < 4; ++f) \
        _Pragma("unroll") \
        for (int g = 0; g < (gn_); ++g) { \
            acc[(mh_) * 4 + f][(g0_) + g] = __builtin_amdgcn_mfma_f32_16x16x32_f16( \
                af[f][0], bf[g][0], acc[(mh_) * 4 + f][(g0_) + g], 0, 0, 0); \
            acc[(mh_) * 4 + f][(g0_) + g] = __builtin_amdgcn_mfma_f32_16x16x32_f16( \
                af[f][1], bf[g][1], acc[(mh_) * 4 + f][(g0_) + g], 0, 0, 0); \
        } \
    __builtin_amdgcn_s_setprio(0); }

    // prologue: tile 0, order B0,B1,B2,A0,A2,A1,A3
    SU_B(0, 0) SU_B(1, 0) SU_B(2, 0)
    SU_A(0, 0) SU_A(2, 0) SU_A(1, 0) SU_A(3, 0)

    for (int t = 0; t < 15; ++t) {
        const int bufA = (t & 1) * 32768;
        const int bufB = 65536 + (t & 1) * 24576;
        PH(0, 0, 2, bufA, bufB, VMW2, { SU_B(0, t + 1) SU_B(1, t + 1) })
        PH(0, 2, 1, bufA, bufB, ,     { SU_B(2, t + 1) })
        PH(1, 0, 2, bufA, bufB, VMW3, { SU_A(0, t + 1) SU_A(2, t + 1) })
        PH(1, 2, 1, bufA, bufB, ,     { SU_A(1, t + 1) SU_A(3, t + 1) })
    }
    // t = 15 (buf1), no staging
    PH(0, 0, 2, 32768, 65536 + 24576, VMW2, {})
    PH(0, 2, 1, 32768, 65536 + 24576, ,     {})
    PH(1, 0, 2, 32768, 65536 + 24576, VMW0, {})
    PH(1, 2, 1, 32768, 65536 + 24576, ,     {})

#undef SU_A
#undef SU_B
#undef VMW2
#undef VMW3
#undef VMW0
#undef PH

    // fused epilogue -> Qf (scaled) / Kf [bh][s][64], VfT [bh][d][s]
    const int rowb = m0 + wr * 128 + (l >> 4) * 4;
    const int colb = n0 + wc * 48 + col16;
    #pragma unroll
    for (int n = 0; n < 3; ++n) {
        int col = colb + n * 16;
        int h = col / 192;
        int rem = col - h * 192;
        int part = rem >> 6, d = rem & 63;   // wave-uniform
        float bv = bias[col];
        #pragma unroll
        for (int m = 0; m < 8; ++m) {
            int r0 = rowb + m * 16;
            int b = r0 >> 11, s0r = r0 & 2047;
            int bh = b * 16 + h;
            if (part == 0) {
                #pragma unroll
                for (int j = 0; j < 4; ++j)
                    Qf[((size_t)bh * 2048 + s0r + j) * 64 + d] =
                        (_Float16)((acc[m][n][j] + bv) * QSCALE);
            } else if (part == 1) {
                #pragma unroll
                for (int j = 0; j < 4; ++j)
                    Kf[((size_t)bh * 2048 + s0r + j) * 64 + d] = (_Float16)(acc[m][n][j] + bv);
            } else {
                half4 pk;
                pk[0] = (_Float16)(acc[m][n][0] + bv);
                pk[1] = (_Float16)(acc[m][n][1] + bv);
                pk[2] = (_Float16)(acc[m][n][2] + bv);
                pk[3] = (_Float16)(acc[m][n][3] + bv);
                *(half4*)&VfT[((size_t)bh * 64 + d) * 2048 + s0r] = pk;
            }
        }
    }
}

// out[M,N] = A[M,K] @ B[N,K]^T + bias, f32 out. 128x64 tile, 3-buffer pipeline.
__global__ __launch_bounds__(256, 2) void gemm_o(
    const _Float16* __restrict__ A, const _Float16* __restrict__ B,
    const float* __restrict__ bias, float* __restrict__ C,
    int M, int N, int K) {
    __shared__ __align__(1024) unsigned char smem[36864];  // 3 x (A 8K + B 4K)
    const int tid = threadIdx.x;
    const int l = tid & 63, w = tid >> 6;
    const int wr = w >> 1, wc = w & 1;
    const int nwg = gridDim.x * gridDim.y;
    const int bid = blockIdx.y * gridDim.x + blockIdx.x;
    const int swz = (bid & 7) * (nwg >> 3) + (bid >> 3);
    const int m0 = (swz / gridDim.x) * 128, n0 = (swz % gridDim.x) * 64;
    const int srow = tid >> 2;
    const int schunk = (tid & 3) ^ ((srow >> 1) & 3);
    const size_t gA0 = (size_t)(m0 + srow) * K + schunk * 8;
    const size_t gA1 = gA0 + (size_t)64 * K;
    const size_t gB0 = (size_t)(n0 + srow) * K + schunk * 8;
    unsigned char* ldsW = smem + w * 1024;
    const int col16 = l & 15, kc = l >> 4;
    const int ra0 = wr * 64 + col16;
    const int offA = ra0 * 64 + ((kc ^ ((ra0 >> 1) & 3)) * 16);
    const int rb0 = wc * 32 + col16;
    const int offB = rb0 * 64 + ((kc ^ ((rb0 >> 1) & 3)) * 16);
    f32x4 acc[4][2] = {};

#define OSTAGE(k0_, buf_)                                                              \
    load_lds16(A + gA0 + (k0_), ldsW + (buf_) * 12288 + 0);                            \
    load_lds16(A + gA1 + (k0_), ldsW + (buf_) * 12288 + 4096);                         \
    load_lds16(B + gB0 + (k0_), ldsW + (buf_) * 12288 + 8192);
#define OSTEP(s_, buf_, VM, dostage)                                                   \
    asm volatile("s_waitcnt " VM ::: "memory");                                        \
    __builtin_amdgcn_sched_barrier(0);                                                 \
    __builtin_amdgcn_s_barrier();                                                      \
    if (dostage) { OSTAGE(((s_) + 2) * 32, ((buf_) + 2) % 3) }                         \
    {                                                                                  \
        const unsigned char* bs = smem + (buf_) * 12288;                               \
        half8 af[4], bf[2];                                                            \
        _Pragma("unroll")                                                              \
        for (int m = 0; m < 4; ++m) af[m] = *(const half8*)(bs + offA + m * 1024);     \
        _Pragma("unroll")                                                              \
        for (int n = 0; n < 2; ++n) bf[n] = *(const half8*)(bs + 8192 + offB + n * 1024); \
        _Pragma("unroll")                                                              \
        for (int m = 0; m < 4; ++m)                                                    \
            _Pragma("unroll")                                                          \
            for (int n = 0; n < 2; ++n)                                                \
                acc[m][n] = __builtin_amdgcn_mfma_f32_16x16x32_f16(af[m], bf[n], acc[m][n], 0, 0, 0); \
    }

    OSTAGE(0, 0)
    OSTAGE(32, 1)
    for (int t = 0; t < 30; t += 3) {
        OSTEP(t, 0, "vmcnt(3)", 1)
        OSTEP(t + 1, 1, "vmcnt(3)", 1)
        OSTEP(t + 2, 2, "vmcnt(3)", 1)
    }
    OSTEP(30, 0, "vmcnt(3)", 0)
    OSTEP(31, 1, "vmcnt(0)", 0)
#undef OSTAGE
#undef OSTEP

    const int rowb = m0 + wr * 64 + (l >> 4) * 4;
    const int colb = n0 + wc * 32 + col16;
    float bv[2];
    #pragma unroll
    for (int n = 0; n < 2; ++n) bv[n] = bias[colb + n * 16];
    #pragma unroll
    for (int m = 0; m < 4; ++m)
        #pragma unroll
        for (int j = 0; j < 4; ++j) {
            float* crow = C + (size_t)(rowb + m * 16 + j) * N + colb;
            #pragma unroll
            for (int n = 0; n < 2; ++n) crow[n * 16] = acc[m][n][j] + bv[n];
        }
}

// MFMA flash attention (plateau version): 32x32 f16, in-register P,
// absolute-score softmax, 3-buffer K/V, counted vmcnt, 8 waves, q-tile 256,
// grid remapped so a head's 8 q-blocks share one XCD.
__global__ __launch_bounds__(512, 2) void mfma_attn(
    const _Float16* __restrict__ Qf, const _Float16* __restrict__ Kf,
    const _Float16* __restrict__ VfT, _Float16* __restrict__ vals) {
    __shared__ __align__(1024) unsigned char smem[49152];
    const int tid = threadIdx.x;
    const int l = tid & 63, w = tid >> 6;
    const int l31 = l & 31, hl = l >> 5;
    const int hwbid = blockIdx.y * gridDim.x + blockIdx.x;
    const int q_t = (hwbid >> 3) & 7;
    const int bh = (hwbid & 7) + ((hwbid >> 6) << 3);
    const int q0 = q_t * 256;
    const int h = bh & 15, b = bh >> 4;

    half8 qf[4];
    {
        const _Float16* qp = Qf + ((size_t)bh * 2048 + q0 + w * 32 + l31) * 64 + hl * 8;
        #pragma unroll
        for (int c = 0; c < 4; ++c) qf[c] = *(const half8*)(qp + c * 16);
    }
    f32x16 zvec = {};
    f32x16 o0 = {}, o1 = {};
    float mshift = 0.f, lsum = 0.f;

    const _Float16* Kg = Kf + (size_t)bh * 2048 * 64;
    const _Float16* Vg = VfT + (size_t)bh * 64 * 2048;

    int offK, offV;
    {
        int row2 = w * 4 + (l >> 4);
        int slot = (l & 15) ^ (row2 & 15);
        int row = row2 * 2 + (slot >> 3);
        int chunk = slot & 7;
        offK = row * 64 + chunk * 8;
        offV = row * 2048 + chunk * 8;
    }
    const int sbase = (l31 & 1) * 8;
    const int xr = (l31 >> 1) & 15;
    const int rb0 = (l31 >> 1) * 256;

    #define STAGE(kt0, buf)                                                            \
        {                                                                              \
            unsigned char* bK = smem + (buf) * 8192 + w * 1024;                        \
            unsigned char* bV = smem + 24576 + (buf) * 8192 + w * 1024;                \
            load_lds16(Kg + (size_t)(kt0) * 64 + offK, bK);                            \
            load_lds16(Vg + (kt0) + offV, bV);                                         \
        }

    #define QK_TILE(kb, D0, D1)                                                        \
        {                                                                              \
            const unsigned char* Ksb_ = smem + (kb) * 8192;                            \
            {                                                                          \
                int chOff = ((sbase + hl) ^ xr) << 4;                                  \
                half8 k0_ = *(const half8*)(Ksb_ + rb0 + chOff);                       \
                half8 k1_ = *(const half8*)(Ksb_ + rb0 + 4096 + chOff);                \
                D0 = __builtin_amdgcn_mfma_f32_32x32x16_f16(k0_, qf[0], zvec, 0, 0, 0);\
                D1 = __builtin_amdgcn_mfma_f32_32x32x16_f16(k1_, qf[0], zvec, 0, 0, 0);\
            }                                                                          \
            _Pragma("unroll")                                                          \
            for (int kcq = 1; kcq < 4; ++kcq) {                                        \
                int chOff = ((sbase + kcq * 2 + hl) ^ xr) << 4;                        \
                half8 k0_ = *(const half8*)(Ksb_ + rb0 + chOff);                       \
                half8 k1_ = *(const half8*)(Ksb_ + rb0 + 4096 + chOff);                \
                D0 = __builtin_amdgcn_mfma_f32_32x32x16_f16(k0_, qf[kcq], D0, 0, 0, 0);\
                D1 = __builtin_amdgcn_mfma_f32_32x32x16_f16(k1_, qf[kcq], D1, 0, 0, 0);\
            }                                                                          \
        }

    #define SMPV(S0, S1, vb_)                                                          \
        {                                                                              \
            const unsigned char* Vsb_ = smem + 24576 + (vb_) * 8192;                   \
            if (__any(mshift != 0.f)) {                                                \
                _Pragma("unroll")                                                      \
                for (int r = 0; r < 16; ++r) { S0[r] -= mshift; S1[r] -= mshift; }     \
            }                                                                          \
            float r0 = 0.f, r1 = 0.f, r2 = 0.f, r3 = 0.f;                              \
            unsigned int a[2][8];                                                      \
            _Pragma("unroll")                                                          \
            for (int j = 0; j < 8; ++j) {                                              \
                float p0 = __builtin_amdgcn_exp2f(S0[2 * j]);                          \
                float p1 = __builtin_amdgcn_exp2f(S0[2 * j + 1]);                      \
                float q0_ = __builtin_amdgcn_exp2f(S1[2 * j]);                         \
                float q1_ = __builtin_amdgcn_exp2f(S1[2 * j + 1]);                     \
                r0 += p0; r1 += p1; r2 += q0_; r3 += q1_;                              \
                a[0][j] = __builtin_bit_cast(unsigned int, __builtin_amdgcn_cvt_pkrtz(p0, p1));   \
                a[1][j] = __builtin_bit_cast(unsigned int, __builtin_amdgcn_cvt_pkrtz(q0_, q1_)); \
            }                                                                          \
            float rsum = (r0 + r1) + (r2 + r3);                                        \
            if (__any(rsum > 32768.f)) {                                               \
                float pmax = S0[0];                                                    \
                _Pragma("unroll")                                                      \
                for (int r = 1; r < 16; ++r) pmax = fmaxf(pmax, S0[r]);                \
                _Pragma("unroll")                                                      \
                for (int r = 0; r < 16; ++r) pmax = fmaxf(pmax, S1[r]);                \
                pmax = fmaxf(pmax, __shfl_xor(pmax, 32, 64));                          \
                float d_ = fmaxf(pmax, 0.f);                                           \
                float corr = __builtin_amdgcn_exp2f(-d_);                              \
                _Pragma("unroll")                                                      \
                for (int r = 0; r < 16; ++r) { S0[r] -= d_; S1[r] -= d_; }             \
                _Pragma("unroll")                                                      \
                for (int r = 0; r < 16; ++r) { o0[r] *= corr; o1[r] *= corr; }         \
                lsum *= corr;                                                          \
                mshift += d_;                                                          \
                r0 = r1 = r2 = r3 = 0.f;                                               \
                _Pragma("unroll")                                                      \
                for (int j = 0; j < 8; ++j) {                                          \
                    float p0 = __builtin_amdgcn_exp2f(S0[2 * j]);                      \
                    float p1 = __builtin_amdgcn_exp2f(S0[2 * j + 1]);                  \
                    float q0_ = __builtin_amdgcn_exp2f(S1[2 * j]);                     \
                    float q1_ = __builtin_amdgcn_exp2f(S1[2 * j + 1]);                 \
                    r0 += p0; r1 += p1; r2 += q0_; r3 += q1_;                          \
                    a[0][j] = __builtin_bit_cast(unsigned int, __builtin_amdgcn_cvt_pkrtz(p0, p1));   \
                    a[1][j] = __builtin_bit_cast(unsigned int, __builtin_amdgcn_cvt_pkrtz(q0_, q1_)); \
                }                                                                      \
                rsum = (r0 + r1) + (r2 + r3);                                          \
            }                                                                          \
            lsum += rsum;                                                              \
            _Pragma("unroll")                                                          \
            for (int c = 0; c < 2; ++c) {                                              \
                pl32swap(a[c][0], a[c][2]);                                            \
                pl32swap(a[c][1], a[c][3]);                                            \
                pl32swap(a[c][4], a[c][6]);                                            \
                pl32swap(a[c][5], a[c][7]);                                            \
            }                                                                          \
            _Pragma("unroll")                                                          \
            for (int kk = 0; kk < 4; ++kk) {                                           \
                u32x4 pw;                                                              \
                pw.x = a[kk >> 1][(kk & 1) * 4 + 0];                                   \
                pw.y = a[kk >> 1][(kk & 1) * 4 + 1];                                   \
                pw.z = a[kk >> 1][(kk & 1) * 4 + 2];                                   \
                pw.w = a[kk >> 1][(kk & 1) * 4 + 3];                                   \
                half8 pf = __builtin_bit_cast(half8, pw);                              \
                int chOff = ((sbase + kk * 2 + hl) ^ xr) << 4;                         \
                half8 v0 = *(const half8*)(Vsb_ + rb0 + chOff);                        \
                half8 v1 = *(const half8*)(Vsb_ + rb0 + 4096 + chOff);                 \
                o0 = __builtin_amdgcn_mfma_f32_32x32x16_f16(v0, pf, o0, 0, 0, 0);      \
                o1 = __builtin_amdgcn_mfma_f32_32x32x16_f16(v1, pf, o1, 0, 0, 0);      \
            }                                                                          \
        }

    #define AITER(tt, kb, VM, dostage)                                                 \
        asm volatile("s_waitcnt " VM ::: "memory");                                    \
        __builtin_amdgcn_sched_barrier(0);                                             \
        __builtin_amdgcn_s_barrier();                                                  \
        if (dostage) STAGE(((tt) + 2) * 64, ((kb) + 2) % 3)                            \
        QK_TILE(kb, sS0, sS1)                                                          \
        SMPV(sS0, sS1, kb)

    STAGE(0, 0)
    STAGE(64, 1)
    f32x16 sS0, sS1;
    for (int t = 0; t < 30; t += 3) {
        AITER(t, 0, "vmcnt(2)", 1)
        AITER(t + 1, 1, "vmcnt(2)", 1)
        AITER(t + 2, 2, "vmcnt(2)", 1)
    }
    AITER(30, 0, "vmcnt(2)", 0)
    AITER(31, 1, "vmcnt(0)", 0)

    // ---- epilogue ----
    lsum += __shfl_xor(lsum, 32, 64);
    float inv = 1.f / lsum;
    size_t orow = ((size_t)(b * 2048 + q0 + w * 32 + l31)) * 1024 + h * 64;
    #pragma unroll
    for (int dc = 0; dc < 2; ++dc) {
        const f32x16* op = dc ? &o1 : &o0;
        #pragma unroll
        for (int rq = 0; rq < 4; ++rq) {
            int d0 = dc * 32 + rq * 8 + hl * 4;
            half4 hv;
            #pragma unroll
            for (int j = 0; j < 4; ++j) hv[j] = (_Float16)((*op)[rq * 4 + j] * inv);
            *(half4*)(vals + orow + d0) = hv;
        }
    }
}

extern "C" void kernel_launch(void* const* d_in, const int* in_sizes, int n_in,
                              void* d_out, int out_size, void* d_ws, size_t ws_size,
                              hipStream_t stream) {
    const float* x     = (const float*)d_in[0];
    const float* w_qkv = (const float*)d_in[1];
    const float* b_qkv = (const float*)d_in[2];
    const float* w_o   = (const float*)d_in[3];
    const float* b_o   = (const float*)d_in[4];
    float* out = (float*)d_out;

    const int B = 2, S = 2048, D = 1024;
    const int M = B * S;          // 4096
    const int N1 = 3 * D;         // 3072
    const int BH = B * NHEADS;    // 32

    _Float16* xf  = (_Float16*)d_ws;                  // [4096,1024]
    _Float16* wqf = xf  + (size_t)M * D;              // [3072,1024]
    _Float16* wof = wqf + (size_t)N1 * D;             // [1024,1024]
    _Float16* Qf  = wof + (size_t)D * D;              // [32,2048,64]
    _Float16* Kf  = Qf  + (size_t)BH * S * HD;
    _Float16* VfT = Kf  + (size_t)BH * S * HD;        // [32,64,2048]
    _Float16* vals = xf;   // reuse x-f16 space after gemm_qkv

    // 0) all f32->f16 conversions in one launch
    cvt_all<<<(NX + NWQ + NWO) / 2048, 256, 0, stream>>>(x, w_qkv, w_o, xf, wqf, wof);

    // 1) fused QKV projection, 256x192 8-phase, grid 256 (full CU fill)
    gemm_qkv<<<dim3(16, 16), 512, 0, stream>>>(xf, wqf, b_qkv, Qf, Kf, VfT);

    // 2) MFMA flash attention (32x32 f16, counted-vmcnt, XCD-grouped)
    mfma_attn<<<dim3(S / 256, BH), 512, 0, stream>>>(Qf, Kf, VfT, vals);

    // 3) out = vals @ w_o^T + b_o  (128x64 tile, counted-vmcnt pipeline)
    gemm_o<<<dim3(D / 64, M / 128), 256, 0, stream>>>(vals, wof, b_o, out, M, D, D);
}